// Round 1
// 64.396 us; speedup vs baseline: 1.0318x; 1.0318x over previous
//
#include <hip/hip_runtime.h>

#define NQ 11
#define NL 4
#define NF 8
#define DIM 2048   // 2^11
#define NGATES (NL * NQ)  // 44

// Composed permutation of the CNOT ring (0,1)(1,2)...(9,10)(10,0).
// s_after_cnots[i] = s_before[ring_perm(i)]  (verified absmax==0 prior session).
// Linear over GF(2): ring_perm(a^b) = ring_perm(a)^ring_perm(b).
// Closed form: z_b = y_b^y_{b+1} (b=0..8), z_9 = y_9^y_10^y_0, z_10 = y_10^y_0.
// Inverse (used in fused measurement): bit_p(rp^-1(b)) = parity(b & M_p) with
//   M_10 = 0x3FF, M_9 = 0x600, M_8 = 0x700, M_7 = 0x780.
__host__ __device__ constexpr int ring_perm(int y) {
    int z = y ^ ((y & 1) << 10);
    for (int k = 10; k >= 1; --k)
        z ^= ((z >> (11 - k)) & 1) << (10 - k);
    return z;
}

// XOR bank swizzle: bijective, only touches bits 0..4 (chunk-preserving).
__device__ __forceinline__ int swz(int i) { return i ^ ((i >> 5) & 31); }

// Compiler-only reorder fence; HW DS in-order per wave handles the rest.
__device__ __forceinline__ void wave_sync() { __builtin_amdgcn_wave_barrier(); }

__device__ __forceinline__ float2 cmul(float2 a, float2 b) {
    return make_float2(a.x * b.x - a.y * b.y, a.x * b.y + a.y * b.x);
}

__device__ __forceinline__ void rot_pair(float2& a, float2& c,
                                         const float4 M0, const float4 M1) {
    float2 na, nc;
    na.x = M0.x * a.x - M0.y * a.y + M0.z * c.x - M0.w * c.y;
    na.y = M0.x * a.y + M0.y * a.x + M0.z * c.y + M0.w * c.x;
    nc.x = M1.x * a.x - M1.y * a.y + M1.z * c.x - M1.w * c.y;
    nc.y = M1.x * a.y + M1.y * a.x + M1.z * c.y + M1.w * c.x;
    a = na; c = nc;
}

// One LDS pass applying 3 single-qubit gates at bit positions P2>P1>P0.
// If PERM, reads are routed through ring_perm (folds the previous layer's
// CNOT ring into this pass's gather). Writes go to logical addresses.
template<int P2, int P1, int P0, bool PERM>
__device__ __forceinline__ void group3(const float2* __restrict__ src,
                                       float2* __restrict__ dst,
                                       const float (*gm)[8], int g, int base) {
    constexpr int E2 = 1 << P2, E1 = 1 << P1, E0 = 1 << P0;
    constexpr int K2 = PERM ? ring_perm(1 << P2) : (1 << P2);
    constexpr int K1 = PERM ? ring_perm(1 << P1) : (1 << P1);
    constexpr int K0 = PERM ? ring_perm(1 << P0) : (1 << P0);

    const float4* mA = (const float4*)gm[g];
    const float4* mB = (const float4*)gm[g + 1];
    const float4* mC = (const float4*)gm[g + 2];
    const float4 A0 = mA[0], A1 = mA[1];
    const float4 B0 = mB[0], B1 = mB[1];
    const float4 C0 = mC[0], C1 = mC[1];

    const int rb = PERM ? ring_perm(base) : base;
    float2 s[8];
#pragma unroll
    for (int k = 0; k < 8; ++k) {
        const int idx = rb ^ ((k & 4) ? K2 : 0) ^ ((k & 2) ? K1 : 0) ^ ((k & 1) ? K0 : 0);
        s[k] = src[swz(idx)];
    }
    rot_pair(s[0], s[4], A0, A1); rot_pair(s[1], s[5], A0, A1);
    rot_pair(s[2], s[6], A0, A1); rot_pair(s[3], s[7], A0, A1);
    rot_pair(s[0], s[2], B0, B1); rot_pair(s[1], s[3], B0, B1);
    rot_pair(s[4], s[6], B0, B1); rot_pair(s[5], s[7], B0, B1);
    rot_pair(s[0], s[1], C0, C1); rot_pair(s[2], s[3], C0, C1);
    rot_pair(s[4], s[5], C0, C1); rot_pair(s[6], s[7], C0, C1);
#pragma unroll
    for (int k = 0; k < 8; ++k) {
        const int a = base | ((k & 4) ? E2 : 0) | ((k & 2) ? E1 : 0) | ((k & 1) ? E0 : 0);
        dst[swz(a)] = s[k];
    }
}

// 2-qubit group at bit positions (1,0), WAVE-LOCAL mapping:
// thread t owns amps (t<<3)+{0..7} -> amp bits {10,9} == wave id.
__device__ __forceinline__ void group2q(float2* buf, const float (*gm)[8],
                                        int g, int t) {
    const float4* mB = (const float4*)gm[g];
    const float4* mC = (const float4*)gm[g + 1];
    const float4 B0 = mB[0], B1 = mB[1];
    const float4 C0 = mC[0], C1 = mC[1];
#pragma unroll
    for (int j = 0; j < 2; ++j) {
        const int base = (t << 3) | (j << 2);
        float2 s[4];
#pragma unroll
        for (int k = 0; k < 4; ++k) s[k] = buf[swz(base | k)];
        rot_pair(s[0], s[2], B0, B1); rot_pair(s[1], s[3], B0, B1);
        rot_pair(s[0], s[1], C0, C1); rot_pair(s[2], s[3], C0, C1);
#pragma unroll
        for (int k = 0; k < 4; ++k) buf[swz(base | k)] = s[k];
    }
}

// Final layer's (1,0) gates fused with the measurement: apply gates in
// registers, then accumulate signed probabilities directly. Signs come from
// the INVERSE ring perm (the final CNOT ring is never materialized):
// post-ring index a = rp^-1(b); bit10(a)=par(b&0x3FF), bit9=par(b&0x600),
// bit8=par(b&0x700), bit7=par(b&0x780). Low bits of b (0..2) only intersect
// the q0 mask, so q1..q3 signs are per-thread constants -> +-Psum.
__device__ __forceinline__ void group2q_meas(const float2* __restrict__ buf,
                                             const float (*gm)[8], int g, int t,
                                             float v[4]) {
    const float4* mB = (const float4*)gm[g];
    const float4* mC = (const float4*)gm[g + 1];
    const float4 B0 = mB[0], B1 = mB[1];
    const float4 C0 = mC[0], C1 = mC[1];
    const int tb = t << 3;
    const int p0 = __popc(tb & 0x3FF) & 1;
    const int p1 = __popc(tb & 0x600) & 1;
    const int p2 = __popc(tb & 0x700) & 1;
    const int p3 = __popc(tb & 0x780) & 1;
    float Psum = 0.f, Aalt = 0.f;
#pragma unroll
    for (int j = 0; j < 2; ++j) {
        const int base = tb | (j << 2);
        float2 s[4];
#pragma unroll
        for (int k = 0; k < 4; ++k) s[k] = buf[swz(base | k)];
        rot_pair(s[0], s[2], B0, B1); rot_pair(s[1], s[3], B0, B1);
        rot_pair(s[0], s[1], C0, C1); rot_pair(s[2], s[3], C0, C1);
#pragma unroll
        for (int k = 0; k < 4; ++k) {
            const float p = s[k].x * s[k].x + s[k].y * s[k].y;
            Psum += p;
            Aalt += (__popc((j << 2) | k) & 1) ? -p : p;   // folds per unrolled iter
        }
    }
    v[0] = p0 ? -Aalt : Aalt;
    v[1] = p1 ? -Psum : Psum;
    v[2] = p2 ? -Psum : Psum;
    v[3] = p3 ? -Psum : Psum;
}

__global__ __launch_bounds__(256)
void qsim_kernel(const float* __restrict__ X, const float* __restrict__ W,
                 const float* __restrict__ Bi, float* __restrict__ out)
{
    __shared__ float2 bufA[DIM];
    __shared__ float2 bufB[DIM];
    __shared__ __align__(16) float gm[NGATES][8];
    __shared__ float sc[192][2];   // per-angle {sin, cos}, wave-local layout
    __shared__ float red[4][4];

    const int b = blockIdx.x;
    const int t = threadIdx.x;

    // --- fused stage 1+2: 21 gates per wave, 3 angle slots per gate.
    // All three sincos AND the assembler for a gate live in ONE wave, so the
    // sc handoff needs only per-wave in-order DS (wave_sync), no barrier.
    {
        const int sl = t & 63;
        const int g = 21 * (t >> 6) + sl / 3;
        const int c = sl % 3;
        if (sl < 63 && g < NGATES) {
            const int base = g * 3;
            const float x0 = X[b * NF + ((base + 0) & 7)];
            const float x1 = X[b * NF + ((base + 1) & 7)];
            const float x2 = X[b * NF + ((base + 2) & 7)];
            const float phi   = x0 * W[base + 0] + Bi[base + 0];
            const float theta = x1 * W[base + 1] + Bi[base + 1];
            const float omega = x2 * W[base + 2] + Bi[base + 2];
            const float arg = (c == 0) ? 0.5f * theta
                            : (c == 1) ? 0.5f * (phi + omega)
                                       : 0.5f * (phi - omega);
            float s_, c_; sincosf(arg, &s_, &c_);
            sc[t][0] = s_; sc[t][1] = c_;
        }
        wave_sync();
        if (sl < 63 && g < NGATES && c == 0) {
            const float sh  = sc[t][0],     ch  = sc[t][1];
            const float spo = sc[t + 1][0], cpo = sc[t + 1][1];
            const float spm = sc[t + 2][0], cpm = sc[t + 2][1];
            gm[g][0] =  cpo * ch;  gm[g][1] = -spo * ch;   // m00
            gm[g][2] = -cpm * sh;  gm[g][3] = -spm * sh;   // m01
            gm[g][4] =  cpm * sh;  gm[g][5] = -spm * sh;   // m10
            gm[g][6] =  cpo * ch;  gm[g][7] =  spo * ch;   // m11
        }
    }
    __syncthreads();

    float2* S = bufA;
    float2* T = bufB;

    // --- layer 0 closed form: product state amp[x] = prod_q Mq[bit](0) ---
    {
        float2 c0[11], c1[11];
#pragma unroll
        for (int q = 0; q < 11; ++q) {
            c0[q] = make_float2(gm[q][0], gm[q][1]);   // m00
            c1[q] = make_float2(gm[q][4], gm[q][5]);   // m10
        }
        float2 P = ((t >> 0) & 1) ? c1[10] : c0[10];
#pragma unroll
        for (int bbit = 1; bbit < 8; ++bbit)
            P = cmul(P, ((t >> bbit) & 1) ? c1[10 - bbit] : c0[10 - bbit]);
        float2 t2[4];
        t2[0] = cmul(c0[1], c0[0]);
        t2[1] = cmul(c1[1], c0[0]);
        t2[2] = cmul(c0[1], c1[0]);
        t2[3] = cmul(c1[1], c1[0]);
#pragma unroll
        for (int k = 0; k < 8; ++k) {
            const float2 h = cmul((k & 1) ? c1[2] : c0[2], t2[k >> 1]);
            S[swz(t + 256 * k)] = cmul(P, h);
        }
    }
    __syncthreads();

    // layers 1..3. Only the perm-gather pass is cross-wave; the inner passes
    // keep each wave inside its own 512-amp chunk (amp bits {10,9} == wave
    // id; swz only touches bits 0..4), so they need no s_barrier — per-wave
    // in-order DS handles RAW through LDS. The final layer's (1,0) gates are
    // fused with the measurement, dropping the last round-trip + 2 barriers.
#pragma unroll
    for (int l = 1; l < NL; ++l) {
        group3<10, 9, 8, true>(S, T, gm, l * NQ + 0, t); { float2* x = S; S = T; T = x; }
        __syncthreads();   // cross-wave pass done; chunks now private
        const int base765 = ((t >> 5) << 8) | (t & 31);
        const int base432 = ((t >> 2) << 5) | (t & 3);
        group3<7, 6, 5, false>(S, S, gm, l * NQ + 3, base765);  wave_sync();
        group3<4, 3, 2, false>(S, S, gm, l * NQ + 6, base432);  wave_sync();
        if (l < NL - 1) {
            group2q(S, gm, l * NQ + 9, t);
            __syncthreads();   // publish chunks before next cross-wave gather
        }
    }

    // measurement fused with layer 3's (1,0) gates; final ring folded as
    // inverse-perm parity masks (no gather pass, no extra barrier).
    float v[4];
    group2q_meas(S, gm, (NL - 1) * NQ + 9, t, v);

#pragma unroll
    for (int q = 0; q < 4; ++q)
#pragma unroll
        for (int off = 32; off >= 1; off >>= 1)
            v[q] += __shfl_down(v[q], off, 64);
    if ((t & 63) == 0) {
#pragma unroll
        for (int q = 0; q < 4; ++q) red[t >> 6][q] = v[q];
    }
    __syncthreads();
    if (t < 4) {
        out[b * 4 + t] = red[0][t] + red[1][t] + red[2][t] + red[3][t];
    }
}

extern "C" void kernel_launch(void* const* d_in, const int* in_sizes, int n_in,
                              void* d_out, int out_size, void* d_ws, size_t ws_size,
                              hipStream_t stream) {
    const float* X  = (const float*)d_in[0];   // (16, 8)
    const float* W  = (const float*)d_in[1];   // (4, 11, 3)
    const float* Bi = (const float*)d_in[2];   // (4, 11, 3)
    float* out = (float*)d_out;                // (16, 4)
    qsim_kernel<<<16, 256, 0, stream>>>(X, W, Bi, out);
}